// Round 3
// baseline (78.877 us; speedup 1.0000x reference)
//
#include <hip/hip_runtime.h>

// ---------------------------------------------------------------------------
// Hopfield block, B=131072 independent problems of S=14, D=16 -> softmax(7).
// Algebra folded so per-batch work is:
//   LN -> t = xh@M -> scores = t.xh^T + rho[k] -> softmax -> a = wm@A ->
//   z[c] = sum_k a_k (xh[k].W2[c]) + const2[c] -> softmax7
// Lane mapping: 16 lanes per batch, lane = seq row. All cross-lane via DPP.
// ---------------------------------------------------------------------------

#define NBATCH 131072

// DPP helpers: rotation within 16-lane row / quad-perm butterflies.
#define ROR(x,N) __int_as_float(__builtin_amdgcn_update_dpp(0, __float_as_int(x), 0x120 + (N), 0xF, 0xF, false))
#define QPF(x,C) __int_as_float(__builtin_amdgcn_update_dpp(0, __float_as_int(x), (C), 0xF, 0xF, false))

// one d-step of the all-pairs score matmul: s_j += t[d] * xh[d]@lane(rot j)
#define SC(d) { const float td = tt[d]; const float xd = xh[d];     \
    s0  = fmaf(td, xd,          s0 );                               \
    s1  = fmaf(td, ROR(xd,1),   s1 );                               \
    s2  = fmaf(td, ROR(xd,2),   s2 );                               \
    s3  = fmaf(td, ROR(xd,3),   s3 );                               \
    s4  = fmaf(td, ROR(xd,4),   s4 );                               \
    s5  = fmaf(td, ROR(xd,5),   s5 );                               \
    s6  = fmaf(td, ROR(xd,6),   s6 );                               \
    s7  = fmaf(td, ROR(xd,7),   s7 );                               \
    s8  = fmaf(td, ROR(xd,8),   s8 );                               \
    s9  = fmaf(td, ROR(xd,9),   s9 );                               \
    s10 = fmaf(td, ROR(xd,10),  s10);                               \
    s11 = fmaf(td, ROR(xd,11),  s11);                               \
    s12 = fmaf(td, ROR(xd,12),  s12);                               \
    s13 = fmaf(td, ROR(xd,13),  s13);                               \
    s14 = fmaf(td, ROR(xd,14),  s14);                               \
    s15 = fmaf(td, ROR(xd,15),  s15); }

// ---------------------------------------------------------------------------
// Pre-kernel: fold weights into ws:
//   ws[0..255]   M0[d][dd] = sum_e Wq'[e,d] Wk'[e,dd]   (Wx' = g_x (.) Wx)
//   ws[256..271] r[dd]     = sum_e bq'[e]  Wk'[e,dd]    (bq' = bq + Wq@b_lnq)
//   ws[272..383] W2[c][d]  = sum_e Wc[c,e] Wv'[e,d],  Wc = Wb@Wo (7x16)
//   ws[384..390] const2[c] = wm_sum*(Wc[c].bv') + wm_sum*(Wb[c].bo)
//                            + bm*sum(Wb[c]) + bb[c]
//   ws[391..404] wm[s]
// ---------------------------------------------------------------------------
__global__ __launch_bounds__(256) void hop_prep(
    const float* __restrict__ gq, const float* __restrict__ bq_ln,
    const float* __restrict__ gk,
    const float* __restrict__ gv, const float* __restrict__ bv_ln,
    const float* __restrict__ Wq, const float* __restrict__ bq,
    const float* __restrict__ Wk,
    const float* __restrict__ Wv, const float* __restrict__ bv,
    const float* __restrict__ Wo, const float* __restrict__ bo,
    const float* __restrict__ Wm, const float* __restrict__ bm,
    const float* __restrict__ Wb, const float* __restrict__ bb,
    float* __restrict__ ws)
{
    __shared__ float WqP[256], WkP[256], WvP[256];
    __shared__ float bqP[16], bvP[16], WcS[112];
    const int t = threadIdx.x;
    {
        const int d = t & 15;
        WqP[t] = Wq[t] * gq[d];
        WkP[t] = Wk[t] * gk[d];
        WvP[t] = Wv[t] * gv[d];
    }
    if (t < 16) {
        float a = bq[t], c = bv[t];
        for (int d = 0; d < 16; ++d) {
            a = fmaf(Wq[t*16+d], bq_ln[d], a);
            c = fmaf(Wv[t*16+d], bv_ln[d], c);
        }
        bqP[t] = a; bvP[t] = c;
    }
    __syncthreads();
    {
        const int d = t >> 4, dd = t & 15;
        float m = 0.f;
        for (int e = 0; e < 16; ++e) m = fmaf(WqP[e*16+d], WkP[e*16+dd], m);
        ws[t] = m;
    }
    if (t < 16) {
        float rr = 0.f;
        for (int e = 0; e < 16; ++e) rr = fmaf(bqP[e], WkP[e*16+t], rr);
        ws[256 + t] = rr;
    }
    if (t < 112) {
        const int c = t >> 4, e = t & 15;
        float s = 0.f;
        for (int o = 0; o < 128; ++o) s = fmaf(Wb[c*128+o], Wo[o*16+e], s);
        WcS[t] = s;
    }
    __syncthreads();
    if (t < 112) {
        const int c = t >> 4, d = t & 15;
        float s = 0.f;
        for (int e = 0; e < 16; ++e) s = fmaf(WcS[c*16+e], WvP[e*16+d], s);
        ws[272 + t] = s;
    }
    if (t < 7) {
        float wmsum = 0.f;
        for (int s = 0; s < 14; ++s) wmsum += Wm[s];
        float s1 = 0.f;
        for (int e = 0; e < 16; ++e) s1 = fmaf(WcS[t*16+e], bvP[e], s1);
        float s2 = 0.f, s3 = 0.f;
        for (int o = 0; o < 128; ++o) { s2 = fmaf(Wb[t*128+o], bo[o], s2); s3 += Wb[t*128+o]; }
        ws[384 + t] = wmsum*s1 + wmsum*s2 + bm[0]*s3 + bb[t];
    }
    if (t < 14) ws[391 + t] = Wm[t];
}

// ---------------------------------------------------------------------------
// Main kernel: 16 lanes per batch (lane = seq row s, rows 14/15 are pads),
// 4 batches per wave. Cross-lane only via DPP (no LDS).
// ---------------------------------------------------------------------------
__global__ __launch_bounds__(256) void hop_main(const float* __restrict__ smp,
                                                const float* __restrict__ W,
                                                float* __restrict__ out)
{
    const int g  = (blockIdx.x * 256 + threadIdx.x) >> 4;   // batch id
    const int ln = threadIdx.x & 15;                        // row s (14,15 pad)
    const float wm_l = (ln < 14) ? W[391 + ln] : 0.0f;
    const int srow = (ln < 14) ? ln : 0;                    // clamp pad reads

    const float4* rp = reinterpret_cast<const float4*>(smp + (size_t)g * 224 + srow * 16);
    const float4 v0 = rp[0], v1 = rp[1], v2 = rp[2], v3 = rp[3];
    float xh[16] = { v0.x, v0.y, v0.z, v0.w,  v1.x, v1.y, v1.z, v1.w,
                     v2.x, v2.y, v2.z, v2.w,  v3.x, v3.y, v3.z, v3.w };

    // LayerNorm stats (lane-local, biased variance, eps inside rsqrt)
    float sm = 0.f, sq = 0.f;
    #pragma unroll
    for (int i = 0; i < 16; ++i) { sm += xh[i]; sq = fmaf(xh[i], xh[i], sq); }
    const float mean = sm * 0.0625f;
    const float var  = fmaf(sq, 0.0625f, -mean * mean);
    const float rstd = __builtin_amdgcn_rsqf(var + 1e-5f);
    const float nmr  = -mean * rstd;
    #pragma unroll
    for (int i = 0; i < 16; ++i) xh[i] = fmaf(xh[i], rstd, nmr);

    // t = xh @ M0   (M0 uniform -> scalar loads)
    float tt[16];
    #pragma unroll
    for (int e = 0; e < 16; ++e) tt[e] = xh[0] * W[e];
    #pragma unroll
    for (int d = 1; d < 16; ++d) {
        const float xd = xh[d];
        #pragma unroll
        for (int e = 0; e < 16; ++e) tt[e] = fmaf(xd, W[d*16 + e], tt[e]);
    }

    // rho[k] = xh[k].r ; pad columns get -1e30 so exp -> 0
    float rho = 0.f;
    #pragma unroll
    for (int d = 0; d < 16; ++d) rho = fmaf(xh[d], W[256 + d], rho);
    rho = (ln < 14) ? rho : -1e30f;

    // scores: s_j = t[s] . xh[sigma_j(s)] + rho[sigma_j(s)]
    float s0 = rho,         s1 = ROR(rho, 1),  s2 = ROR(rho, 2),  s3 = ROR(rho, 3),
          s4 = ROR(rho, 4), s5 = ROR(rho, 5),  s6 = ROR(rho, 6),  s7 = ROR(rho, 7),
          s8 = ROR(rho, 8), s9 = ROR(rho, 9),  s10 = ROR(rho,10), s11 = ROR(rho,11),
          s12 = ROR(rho,12), s13 = ROR(rho,13), s14 = ROR(rho,14), s15 = ROR(rho,15);
    SC(0);  SC(1);  SC(2);  SC(3);  SC(4);  SC(5);  SC(6);  SC(7);
    SC(8);  SC(9);  SC(10); SC(11); SC(12); SC(13); SC(14); SC(15);

    // row softmax (lane-local over the 16 regs)
    const float L2E = 1.4426950408889634f;
    const float mx = fmaxf(
        fmaxf(fmaxf(fmaxf(s0,s1),fmaxf(s2,s3)), fmaxf(fmaxf(s4,s5),fmaxf(s6,s7))),
        fmaxf(fmaxf(fmaxf(s8,s9),fmaxf(s10,s11)), fmaxf(fmaxf(s12,s13),fmaxf(s14,s15))));
    const float nb = -mx * L2E;
    s0  = exp2f(fmaf(s0,  L2E, nb));  s1  = exp2f(fmaf(s1,  L2E, nb));
    s2  = exp2f(fmaf(s2,  L2E, nb));  s3  = exp2f(fmaf(s3,  L2E, nb));
    s4  = exp2f(fmaf(s4,  L2E, nb));  s5  = exp2f(fmaf(s5,  L2E, nb));
    s6  = exp2f(fmaf(s6,  L2E, nb));  s7  = exp2f(fmaf(s7,  L2E, nb));
    s8  = exp2f(fmaf(s8,  L2E, nb));  s9  = exp2f(fmaf(s9,  L2E, nb));
    s10 = exp2f(fmaf(s10, L2E, nb));  s11 = exp2f(fmaf(s11, L2E, nb));
    s12 = exp2f(fmaf(s12, L2E, nb));  s13 = exp2f(fmaf(s13, L2E, nb));
    s14 = exp2f(fmaf(s14, L2E, nb));  s15 = exp2f(fmaf(s15, L2E, nb));
    const float rowsum = (((s0+s1)+(s2+s3)) + ((s4+s5)+(s6+s7)))
                       + (((s8+s9)+(s10+s11)) + ((s12+s13)+(s14+s15)));
    const float f = wm_l * __builtin_amdgcn_rcpf(rowsum);   // wm[s]/rowsum
    s0  *= f; s1  *= f; s2  *= f; s3  *= f; s4  *= f; s5  *= f; s6  *= f; s7  *= f;
    s8  *= f; s9  *= f; s10 *= f; s11 *= f; s12 *= f; s13 *= f; s14 *= f; s15 *= f;

    // a[k] = sum_s wm[s] A[s,k]  (inverse rotations gather to lane k)
    float a = s0;
    a += ROR(s1, 15); a += ROR(s2, 14); a += ROR(s3, 13); a += ROR(s4, 12);
    a += ROR(s5, 11); a += ROR(s6, 10); a += ROR(s7,  9); a += ROR(s8,  8);
    a += ROR(s9,  7); a += ROR(s10, 6); a += ROR(s11, 5); a += ROR(s12, 4);
    a += ROR(s13, 3); a += ROR(s14, 2); a += ROR(s15, 1);

    // z[c] = sum_k a_k (xh[k].W2[c]) + const2[c]; butterfly allreduce over 16
    float z[7];
    #pragma unroll
    for (int c = 0; c < 7; ++c) {
        float wc = xh[0] * W[272 + c*16];
        #pragma unroll
        for (int d = 1; d < 16; ++d) wc = fmaf(xh[d], W[272 + c*16 + d], wc);
        float zc = a * wc;
        zc += QPF(zc, 0xB1);   // xor1
        zc += QPF(zc, 0x4E);   // xor2
        zc += QPF(zc, 0x141);  // row_half_mirror (xor7)
        zc += QPF(zc, 0x140);  // row_mirror (xor15)
        z[c] = zc + W[384 + c];
    }

    // softmax over 7 classes, lane c<7 writes out[b*7+c]
    const float m7 = fmaxf(fmaxf(fmaxf(z[0],z[1]),fmaxf(z[2],z[3])),
                           fmaxf(fmaxf(z[4],z[5]),z[6]));
    const float nb7 = -m7 * L2E;
    #pragma unroll
    for (int c = 0; c < 7; ++c) z[c] = exp2f(fmaf(z[c], L2E, nb7));
    const float s7sum = ((z[0]+z[1]) + (z[2]+z[3])) + ((z[4]+z[5]) + z[6]);
    const float rin = __builtin_amdgcn_rcpf(s7sum);
    float val = z[0];
    val = (ln == 1) ? z[1] : val;
    val = (ln == 2) ? z[2] : val;
    val = (ln == 3) ? z[3] : val;
    val = (ln == 4) ? z[4] : val;
    val = (ln == 5) ? z[5] : val;
    val = (ln == 6) ? z[6] : val;
    if (ln < 7) out[(size_t)g * 7 + ln] = val * rin;
}

extern "C" void kernel_launch(void* const* d_in, const int* in_sizes, int n_in,
                              void* d_out, int out_size, void* d_ws, size_t ws_size,
                              hipStream_t stream) {
    (void)in_sizes; (void)n_in; (void)out_size; (void)ws_size;
    const float* smp = (const float*)d_in[0];
    float* ws = (float*)d_ws;
    hop_prep<<<1, 256, 0, stream>>>(
        (const float*)d_in[1],  (const float*)d_in[2],   // ln_q_g, ln_q_b
        (const float*)d_in[3],                           // ln_k_g
        (const float*)d_in[5],  (const float*)d_in[6],   // ln_v_g, ln_v_b
        (const float*)d_in[7],  (const float*)d_in[8],   // Wq, bq
        (const float*)d_in[9],                           // Wk
        (const float*)d_in[11], (const float*)d_in[12],  // Wv, bv
        (const float*)d_in[13], (const float*)d_in[14],  // Wo, bo
        (const float*)d_in[15], (const float*)d_in[16],  // Wm, bm
        (const float*)d_in[17], (const float*)d_in[18],  // Wb, bb
        ws);
    hop_main<<<NBATCH * 16 / 256, 256, 0, stream>>>(smp, ws, (float*)d_out);
}

// Round 4
// 78.863 us; speedup vs baseline: 1.0002x; 1.0002x over previous
//
#include <hip/hip_runtime.h>

// ---------------------------------------------------------------------------
// Hopfield block, B=131072 independent problems of S=14, D=16 -> softmax(7).
// Algebra folded so per-batch work is:
//   LN -> t = xh@M -> scores = t.xh^T + rho[k] -> softmax -> a = wm@A ->
//   z[c] = sum_k a_k (xh[k].W2[c]) + const2[c] -> softmax7
// Lane mapping: 16 lanes per batch, lane = seq row. All cross-lane via DPP.
// ---------------------------------------------------------------------------

#define NBATCH 131072

// DPP helpers: rotation within 16-lane row / quad-perm butterflies.
#define ROR(x,N) __int_as_float(__builtin_amdgcn_update_dpp(0, __float_as_int(x), 0x120 + (N), 0xF, 0xF, false))
#define QPF(x,C) __int_as_float(__builtin_amdgcn_update_dpp(0, __float_as_int(x), (C), 0xF, 0xF, false))

// one d-step of the all-pairs score matmul: s_j += t[d] * xh[d]@lane(rot j)
#define SC(d) { const float td = tt[d]; const float xd = xh[d];     \
    s0  = fmaf(td, xd,          s0 );                               \
    s1  = fmaf(td, ROR(xd,1),   s1 );                               \
    s2  = fmaf(td, ROR(xd,2),   s2 );                               \
    s3  = fmaf(td, ROR(xd,3),   s3 );                               \
    s4  = fmaf(td, ROR(xd,4),   s4 );                               \
    s5  = fmaf(td, ROR(xd,5),   s5 );                               \
    s6  = fmaf(td, ROR(xd,6),   s6 );                               \
    s7  = fmaf(td, ROR(xd,7),   s7 );                               \
    s8  = fmaf(td, ROR(xd,8),   s8 );                               \
    s9  = fmaf(td, ROR(xd,9),   s9 );                               \
    s10 = fmaf(td, ROR(xd,10),  s10);                               \
    s11 = fmaf(td, ROR(xd,11),  s11);                               \
    s12 = fmaf(td, ROR(xd,12),  s12);                               \
    s13 = fmaf(td, ROR(xd,13),  s13);                               \
    s14 = fmaf(td, ROR(xd,14),  s14);                               \
    s15 = fmaf(td, ROR(xd,15),  s15); }

// ---------------------------------------------------------------------------
// Pre-kernel: fold weights into ws:
//   ws[0..255]   M0[d][dd] = sum_e Wq'[e,d] Wk'[e,dd]   (Wx' = g_x (.) Wx)
//   ws[256..271] r[dd]     = sum_e bq'[e]  Wk'[e,dd]    (bq' = bq + Wq@b_lnq)
//   ws[272..383] W2[c][d]  = sum_e Wc[c,e] Wv'[e,d],  Wc = Wb@Wo (7x16)
//   ws[384..390] const2[c] = wm_sum*(Wc[c].bv') + wm_sum*(Wb[c].bo)
//                            + bm*sum(Wb[c]) + bb[c]
//   ws[391..404] wm[s]
// ---------------------------------------------------------------------------
__global__ __launch_bounds__(256) void hop_prep(
    const float* __restrict__ gq, const float* __restrict__ bq_ln,
    const float* __restrict__ gk,
    const float* __restrict__ gv, const float* __restrict__ bv_ln,
    const float* __restrict__ Wq, const float* __restrict__ bq,
    const float* __restrict__ Wk,
    const float* __restrict__ Wv, const float* __restrict__ bv,
    const float* __restrict__ Wo, const float* __restrict__ bo,
    const float* __restrict__ Wm, const float* __restrict__ bm,
    const float* __restrict__ Wb, const float* __restrict__ bb,
    float* __restrict__ ws)
{
    __shared__ float WqP[256], WkP[256], WvP[256];
    __shared__ float bqP[16], bvP[16], WcS[112];
    const int t = threadIdx.x;
    {
        const int d = t & 15;
        WqP[t] = Wq[t] * gq[d];
        WkP[t] = Wk[t] * gk[d];
        WvP[t] = Wv[t] * gv[d];
    }
    if (t < 16) {
        float a = bq[t], c = bv[t];
        for (int d = 0; d < 16; ++d) {
            a = fmaf(Wq[t*16+d], bq_ln[d], a);
            c = fmaf(Wv[t*16+d], bv_ln[d], c);
        }
        bqP[t] = a; bvP[t] = c;
    }
    __syncthreads();
    {
        const int d = t >> 4, dd = t & 15;
        float m = 0.f;
        for (int e = 0; e < 16; ++e) m = fmaf(WqP[e*16+d], WkP[e*16+dd], m);
        ws[t] = m;
    }
    if (t < 16) {
        float rr = 0.f;
        for (int e = 0; e < 16; ++e) rr = fmaf(bqP[e], WkP[e*16+t], rr);
        ws[256 + t] = rr;
    }
    if (t < 112) {
        const int c = t >> 4, e = t & 15;
        float s = 0.f;
        for (int o = 0; o < 128; ++o) s = fmaf(Wb[c*128+o], Wo[o*16+e], s);
        WcS[t] = s;
    }
    __syncthreads();
    if (t < 112) {
        const int c = t >> 4, d = t & 15;
        float s = 0.f;
        for (int e = 0; e < 16; ++e) s = fmaf(WcS[c*16+e], WvP[e*16+d], s);
        ws[272 + t] = s;
    }
    if (t < 7) {
        float wmsum = 0.f;
        for (int s = 0; s < 14; ++s) wmsum += Wm[s];
        float s1 = 0.f;
        for (int e = 0; e < 16; ++e) s1 = fmaf(WcS[t*16+e], bvP[e], s1);
        float s2 = 0.f, s3 = 0.f;
        for (int o = 0; o < 128; ++o) { s2 = fmaf(Wb[t*128+o], bo[o], s2); s3 += Wb[t*128+o]; }
        ws[384 + t] = wmsum*s1 + wmsum*s2 + bm[0]*s3 + bb[t];
    }
    if (t < 14) ws[391 + t] = Wm[t];
}

// ---------------------------------------------------------------------------
// Main kernel: 16 lanes per batch (lane = seq row s, rows 14/15 are pads),
// 4 batches per wave. Cross-lane only via DPP (no LDS).
// ---------------------------------------------------------------------------
__global__ __launch_bounds__(256) void hop_main(const float* __restrict__ smp,
                                                const float* __restrict__ W,
                                                float* __restrict__ out)
{
    const int g  = (blockIdx.x * 256 + threadIdx.x) >> 4;   // batch id
    const int ln = threadIdx.x & 15;                        // row s (14,15 pad)
    const float wm_l = (ln < 14) ? W[391 + ln] : 0.0f;
    const int srow = (ln < 14) ? ln : 0;                    // clamp pad reads

    const float4* rp = reinterpret_cast<const float4*>(smp + (size_t)g * 224 + srow * 16);
    const float4 v0 = rp[0], v1 = rp[1], v2 = rp[2], v3 = rp[3];
    float xh[16] = { v0.x, v0.y, v0.z, v0.w,  v1.x, v1.y, v1.z, v1.w,
                     v2.x, v2.y, v2.z, v2.w,  v3.x, v3.y, v3.z, v3.w };

    // LayerNorm stats (lane-local, biased variance, eps inside rsqrt)
    float sm = 0.f, sq = 0.f;
    #pragma unroll
    for (int i = 0; i < 16; ++i) { sm += xh[i]; sq = fmaf(xh[i], xh[i], sq); }
    const float mean = sm * 0.0625f;
    const float var  = fmaf(sq, 0.0625f, -mean * mean);
    const float rstd = __builtin_amdgcn_rsqf(var + 1e-5f);
    const float nmr  = -mean * rstd;
    #pragma unroll
    for (int i = 0; i < 16; ++i) xh[i] = fmaf(xh[i], rstd, nmr);

    // t = xh @ M0   (M0 uniform -> scalar loads)
    float tt[16];
    #pragma unroll
    for (int e = 0; e < 16; ++e) tt[e] = xh[0] * W[e];
    #pragma unroll
    for (int d = 1; d < 16; ++d) {
        const float xd = xh[d];
        #pragma unroll
        for (int e = 0; e < 16; ++e) tt[e] = fmaf(xd, W[d*16 + e], tt[e]);
    }

    // rho[k] = xh[k].r ; pad columns get -1e30 so exp -> 0
    float rho = 0.f;
    #pragma unroll
    for (int d = 0; d < 16; ++d) rho = fmaf(xh[d], W[256 + d], rho);
    rho = (ln < 14) ? rho : -1e30f;

    // scores: s_j = t[s] . xh[sigma_j(s)] + rho[sigma_j(s)]
    float s0 = rho,         s1 = ROR(rho, 1),  s2 = ROR(rho, 2),  s3 = ROR(rho, 3),
          s4 = ROR(rho, 4), s5 = ROR(rho, 5),  s6 = ROR(rho, 6),  s7 = ROR(rho, 7),
          s8 = ROR(rho, 8), s9 = ROR(rho, 9),  s10 = ROR(rho,10), s11 = ROR(rho,11),
          s12 = ROR(rho,12), s13 = ROR(rho,13), s14 = ROR(rho,14), s15 = ROR(rho,15);
    SC(0);  SC(1);  SC(2);  SC(3);  SC(4);  SC(5);  SC(6);  SC(7);
    SC(8);  SC(9);  SC(10); SC(11); SC(12); SC(13); SC(14); SC(15);

    // row softmax (lane-local over the 16 regs)
    const float L2E = 1.4426950408889634f;
    const float mx = fmaxf(
        fmaxf(fmaxf(fmaxf(s0,s1),fmaxf(s2,s3)), fmaxf(fmaxf(s4,s5),fmaxf(s6,s7))),
        fmaxf(fmaxf(fmaxf(s8,s9),fmaxf(s10,s11)), fmaxf(fmaxf(s12,s13),fmaxf(s14,s15))));
    const float nb = -mx * L2E;
    s0  = exp2f(fmaf(s0,  L2E, nb));  s1  = exp2f(fmaf(s1,  L2E, nb));
    s2  = exp2f(fmaf(s2,  L2E, nb));  s3  = exp2f(fmaf(s3,  L2E, nb));
    s4  = exp2f(fmaf(s4,  L2E, nb));  s5  = exp2f(fmaf(s5,  L2E, nb));
    s6  = exp2f(fmaf(s6,  L2E, nb));  s7  = exp2f(fmaf(s7,  L2E, nb));
    s8  = exp2f(fmaf(s8,  L2E, nb));  s9  = exp2f(fmaf(s9,  L2E, nb));
    s10 = exp2f(fmaf(s10, L2E, nb));  s11 = exp2f(fmaf(s11, L2E, nb));
    s12 = exp2f(fmaf(s12, L2E, nb));  s13 = exp2f(fmaf(s13, L2E, nb));
    s14 = exp2f(fmaf(s14, L2E, nb));  s15 = exp2f(fmaf(s15, L2E, nb));
    const float rowsum = (((s0+s1)+(s2+s3)) + ((s4+s5)+(s6+s7)))
                       + (((s8+s9)+(s10+s11)) + ((s12+s13)+(s14+s15)));
    const float f = wm_l * __builtin_amdgcn_rcpf(rowsum);   // wm[s]/rowsum
    s0  *= f; s1  *= f; s2  *= f; s3  *= f; s4  *= f; s5  *= f; s6  *= f; s7  *= f;
    s8  *= f; s9  *= f; s10 *= f; s11 *= f; s12 *= f; s13 *= f; s14 *= f; s15 *= f;

    // a[k] = sum_s wm[s] A[s,k]  (inverse rotations gather to lane k)
    float a = s0;
    a += ROR(s1, 15); a += ROR(s2, 14); a += ROR(s3, 13); a += ROR(s4, 12);
    a += ROR(s5, 11); a += ROR(s6, 10); a += ROR(s7,  9); a += ROR(s8,  8);
    a += ROR(s9,  7); a += ROR(s10, 6); a += ROR(s11, 5); a += ROR(s12, 4);
    a += ROR(s13, 3); a += ROR(s14, 2); a += ROR(s15, 1);

    // z[c] = sum_k a_k (xh[k].W2[c]) + const2[c]; butterfly allreduce over 16
    float z[7];
    #pragma unroll
    for (int c = 0; c < 7; ++c) {
        float wc = xh[0] * W[272 + c*16];
        #pragma unroll
        for (int d = 1; d < 16; ++d) wc = fmaf(xh[d], W[272 + c*16 + d], wc);
        float zc = a * wc;
        zc += QPF(zc, 0xB1);   // xor1
        zc += QPF(zc, 0x4E);   // xor2
        zc += QPF(zc, 0x141);  // row_half_mirror (xor7)
        zc += QPF(zc, 0x140);  // row_mirror (xor15)
        z[c] = zc + W[384 + c];
    }

    // softmax over 7 classes, lane c<7 writes out[b*7+c]
    const float m7 = fmaxf(fmaxf(fmaxf(z[0],z[1]),fmaxf(z[2],z[3])),
                           fmaxf(fmaxf(z[4],z[5]),z[6]));
    const float nb7 = -m7 * L2E;
    #pragma unroll
    for (int c = 0; c < 7; ++c) z[c] = exp2f(fmaf(z[c], L2E, nb7));
    const float s7sum = ((z[0]+z[1]) + (z[2]+z[3])) + ((z[4]+z[5]) + z[6]);
    const float rin = __builtin_amdgcn_rcpf(s7sum);
    float val = z[0];
    val = (ln == 1) ? z[1] : val;
    val = (ln == 2) ? z[2] : val;
    val = (ln == 3) ? z[3] : val;
    val = (ln == 4) ? z[4] : val;
    val = (ln == 5) ? z[5] : val;
    val = (ln == 6) ? z[6] : val;
    if (ln < 7) out[(size_t)g * 7 + ln] = val * rin;
}

extern "C" void kernel_launch(void* const* d_in, const int* in_sizes, int n_in,
                              void* d_out, int out_size, void* d_ws, size_t ws_size,
                              hipStream_t stream) {
    (void)in_sizes; (void)n_in; (void)out_size; (void)ws_size;
    const float* smp = (const float*)d_in[0];
    float* ws = (float*)d_ws;
    hop_prep<<<1, 256, 0, stream>>>(
        (const float*)d_in[1],  (const float*)d_in[2],   // ln_q_g, ln_q_b
        (const float*)d_in[3],                           // ln_k_g
        (const float*)d_in[5],  (const float*)d_in[6],   // ln_v_g, ln_v_b
        (const float*)d_in[7],  (const float*)d_in[8],   // Wq, bq
        (const float*)d_in[9],                           // Wk
        (const float*)d_in[11], (const float*)d_in[12],  // Wv, bv
        (const float*)d_in[13], (const float*)d_in[14],  // Wo, bo
        (const float*)d_in[15], (const float*)d_in[16],  // Wm, bm
        (const float*)d_in[17], (const float*)d_in[18],  // Wb, bb
        ws);
    hop_main<<<NBATCH * 16 / 256, 256, 0, stream>>>(smp, ws, (float*)d_out);
}

// Round 6
// 35.246 us; speedup vs baseline: 2.2379x; 2.2375x over previous
//
#include <hip/hip_runtime.h>

// ---------------------------------------------------------------------------
// Hopfield block, B=131072 independent problems of S=14, D=16 -> softmax(7).
// One batch spread over all 64 lanes; the whole pipeline is 4 chained
// v_mfma_f32_16x16x16_f16 ops whose fragment layouts compose exactly:
//   tT = MT@xhT            (D of mfma1 == B-frag of mfma2, + r folded in)
//   SS = xh@(tT+r)         (scores^T: lane holds 4 k's of column s=l&15)
//   P  = xh@W2T            (independent; issued early)
//   G  = (wm/Z * e)^T @ P  (exp'd scores are already an A-frag; P a B-frag)
//   z_c = reduce(G) + const2 -> shared softmax7 across the wave's 4 batches
// Cross-lane: __shfl_xor(16/32) for k-chunk reduces, DPP ring for softmax7.
// ---------------------------------------------------------------------------

#define NBATCH 131072

typedef float    f32x4 __attribute__((ext_vector_type(4)));
typedef _Float16 f16x4 __attribute__((ext_vector_type(4)));
typedef __fp16   h16x2 __attribute__((ext_vector_type(2)));

#define ROR(x,N) __int_as_float(__builtin_amdgcn_update_dpp(0, __float_as_int(x), 0x120 + (N), 0xF, 0xF, false))

static __device__ __forceinline__ f16x4 cvt4(float a, float b, float c, float d) {
    union { f16x4 v; h16x2 h[2]; } u;
    u.h[0] = __builtin_amdgcn_cvt_pkrtz(a, b);
    u.h[1] = __builtin_amdgcn_cvt_pkrtz(c, d);
    return u.v;
}

static __device__ __forceinline__ f32x4 mfma16(f16x4 a, f16x4 b, f32x4 c) {
#if __has_builtin(__builtin_amdgcn_mfma_f32_16x16x16f16)
    return __builtin_amdgcn_mfma_f32_16x16x16f16(a, b, c, 0, 0, 0);
#else
    f32x4 d;
    asm("v_mfma_f32_16x16x16_f16 %0, %1, %2, %3" : "=v"(d) : "v"(a), "v"(b), "v"(c));
    return d;
#endif
}

// ---------------------------------------------------------------------------
// Pre-kernel: fold weights into ws (all f32):
//   ws[  0..255]  MT[dd][d]  = M[d][dd],  M = Wq'^T Wk'  (Wx' = g_x (.) Wx)
//   ws[256..271]  r[dd]      = sum_e bq'[e] Wk'[e,dd]    (bq' = bq + Wq@b_lnq)
//   ws[272..527]  W2pad[c][d] 16x16, rows c=7..15 zero;  W2 = (Wb@Wo)@Wv'
//   ws[528..543]  const2[c] (c<7), zero-padded
//   ws[544..559]  wm[s] (s<14), zero-padded
// ---------------------------------------------------------------------------
__global__ __launch_bounds__(256) void hop_prep(
    const float* __restrict__ gq, const float* __restrict__ bq_ln,
    const float* __restrict__ gk,
    const float* __restrict__ gv, const float* __restrict__ bv_ln,
    const float* __restrict__ Wq, const float* __restrict__ bq,
    const float* __restrict__ Wk,
    const float* __restrict__ Wv, const float* __restrict__ bv,
    const float* __restrict__ Wo, const float* __restrict__ bo,
    const float* __restrict__ Wm, const float* __restrict__ bm,
    const float* __restrict__ Wb, const float* __restrict__ bb,
    float* __restrict__ ws)
{
    __shared__ float WqP[256], WkP[256], WvP[256];
    __shared__ float bqP[16], bvP[16], WcS[112];
    const int t = threadIdx.x;
    {
        const int d = t & 15;
        WqP[t] = Wq[t] * gq[d];
        WkP[t] = Wk[t] * gk[d];
        WvP[t] = Wv[t] * gv[d];
    }
    if (t < 16) {
        float a = bq[t], c = bv[t];
        for (int d = 0; d < 16; ++d) {
            a = fmaf(Wq[t*16+d], bq_ln[d], a);
            c = fmaf(Wv[t*16+d], bv_ln[d], c);
        }
        bqP[t] = a; bvP[t] = c;
    }
    if (t < 112) {   // Wc = Wb@Wo (7x16), depends only on globals
        const int c = t >> 4, e = t & 15;
        float s = 0.f;
        for (int o = 0; o < 128; ++o) s = fmaf(Wb[c*128+o], Wo[o*16+e], s);
        WcS[t] = s;
    }
    __syncthreads();
    {   // MT (transposed M): ws[dd*16+d] = M[d][dd]
        const int dd = t >> 4, d = t & 15;
        float m = 0.f;
        for (int e = 0; e < 16; ++e) m = fmaf(WqP[e*16+d], WkP[e*16+dd], m);
        ws[t] = m;
    }
    if (t < 16) {
        float rr = 0.f;
        for (int e = 0; e < 16; ++e) rr = fmaf(bqP[e], WkP[e*16+t], rr);
        ws[256 + t] = rr;
    }
    {   // W2pad: 16x16, rows c>=7 zero
        const int c = t >> 4, d = t & 15;
        float s = 0.f;
        if (c < 7)
            for (int e = 0; e < 16; ++e) s = fmaf(WcS[c*16+e], WvP[e*16+d], s);
        ws[272 + t] = s;
    }
    if (t < 16) {
        float v = 0.f;
        if (t < 7) {
            float wmsum = 0.f;
            for (int s = 0; s < 14; ++s) wmsum += Wm[s];
            float s1 = 0.f;
            for (int e = 0; e < 16; ++e) s1 = fmaf(WcS[t*16+e], bvP[e], s1);
            float s2 = 0.f, s3 = 0.f;
            for (int o = 0; o < 128; ++o) { s2 = fmaf(Wb[t*128+o], bo[o], s2); s3 += Wb[t*128+o]; }
            v = wmsum*s1 + wmsum*s2 + bm[0]*s3 + bb[t];
        }
        ws[528 + t] = v;
        ws[544 + t] = (t < 14) ? Wm[t] : 0.0f;
    }
}

// ---------------------------------------------------------------------------
// Main kernel: one wave = 4 batches, each batch spread across 64 lanes.
// Fragment convention (v_mfma_f32_16x16x16_f16):
//   A[m][k]: m=l&15, k=4*(l>>4)+i   B[k][n]: n=l&15, k=4*(l>>4)+i
//   D[m][n]: n=l&15, m=4*(l>>4)+i
// ---------------------------------------------------------------------------
__global__ __launch_bounds__(256) void hop_main(const float* __restrict__ smp,
                                                const float* __restrict__ W,
                                                float* __restrict__ out)
{
    const int wid = (blockIdx.x * 256 + threadIdx.x) >> 6;   // global wave id
    const int l   = threadIdx.x & 63;
    const int col = l & 15;    // free-dim index (s / k / c depending on op)
    const int q   = l >> 4;    // k-chunk selector
    const size_t gbase = (size_t)wid * 4;

    // one-time constant fragments (16B-aligned f32 loads, cvt once)
    const float4 mt = *reinterpret_cast<const float4*>(W + col*16 + q*4);        // MT A-frag
    const float4 w2 = *reinterpret_cast<const float4*>(W + 272 + col*16 + q*4);  // W2T B-frag
    const float4 r4 = *reinterpret_cast<const float4*>(W + 256 + q*4);           // r chunk
    const float wm_l = W[544 + col];
    const float c2_l = W[528 + col];
    const f16x4 mtA = cvt4(mt.x, mt.y, mt.z, mt.w);
    const f16x4 w2B = cvt4(w2.x, w2.y, w2.z, w2.w);
    const f32x4 zero = {0.f, 0.f, 0.f, 0.f};
    const float L2E = 1.4426950408889634f;

    const int srow = (col < 14) ? col : 13;                  // clamp pad rows
    const float* bp = smp + gbase * 224 + srow * 16 + q * 4;

    float zb0, zb1, zb2, zb3;
    #pragma unroll
    for (int bb = 0; bb < 4; ++bb) {
        float4 x = *reinterpret_cast<const float4*>(bp + bb * 224);

        // LayerNorm over 16 features spread across the 4 q-groups
        float s1 = (x.x + x.y) + (x.z + x.w);
        float s2 = fmaf(x.x, x.x, fmaf(x.y, x.y, fmaf(x.z, x.z, x.w * x.w)));
        s1 += __shfl_xor(s1, 16, 64);  s2 += __shfl_xor(s2, 16, 64);
        s1 += __shfl_xor(s1, 32, 64);  s2 += __shfl_xor(s2, 32, 64);
        const float mean = s1 * 0.0625f;
        const float var  = fmaf(s2, 0.0625f, -mean * mean);
        const float rstd = __builtin_amdgcn_rsqf(var + 1e-5f);
        const float nmr  = -mean * rstd;
        const f16x4 xhA = cvt4(fmaf(x.x, rstd, nmr), fmaf(x.y, rstd, nmr),
                               fmaf(x.z, rstd, nmr), fmaf(x.w, rstd, nmr));

        // P = xh @ W2^T  (independent of score chain -> issues early)
        f32x4 P = mfma16(xhA, w2B, zero);
        // tT = MT @ xhT
        f32x4 T = mfma16(mtA, xhA, zero);
        // B2 = tT + r (rho folded into score matmul), cvt to B-frag
        const f16x4 B2 = cvt4(T[0] + r4.x, T[1] + r4.y, T[2] + r4.z, T[3] + r4.w);
        // SS = scores^T: lane holds SS[k=4q+i][s=col]
        f32x4 SS = mfma16(xhA, B2, zero);

        // kill pad keys k=14,15 (q==3, regs 2,3)
        const bool hi = (q == 3);
        SS[2] = hi ? -1e30f : SS[2];
        SS[3] = hi ? -1e30f : SS[3];

        // softmax over k (scores bounded -> no max subtraction needed)
        float e0 = __builtin_amdgcn_exp2f(SS[0] * L2E);
        float e1 = __builtin_amdgcn_exp2f(SS[1] * L2E);
        float e2 = __builtin_amdgcn_exp2f(SS[2] * L2E);
        float e3 = __builtin_amdgcn_exp2f(SS[3] * L2E);
        float Z = (e0 + e1) + (e2 + e3);
        Z += __shfl_xor(Z, 16, 64);
        Z += __shfl_xor(Z, 32, 64);
        const float f = wm_l * __builtin_amdgcn_rcpf(Z);     // wm[s]/Z_s (0 for pads)

        // G = (f*e)^T @ P ; exp'd scores are already an A-frag, P a B-frag
        const f16x4 Ef = cvt4(e0 * f, e1 * f, e2 * f, e3 * f);
        const f16x4 Pf = cvt4(P[0], P[1], P[2], P[3]);
        f32x4 G = mfma16(Ef, Pf, zero);

        float zz = (G[0] + G[1]) + (G[2] + G[3]);
        zz += __shfl_xor(zz, 16, 64);
        zz += __shfl_xor(zz, 32, 64);
        zz += c2_l;
        if      (bb == 0) zb0 = zz;
        else if (bb == 1) zb1 = zz;
        else if (bb == 2) zb2 = zz;
        else              zb3 = zz;
    }

    // shared softmax7: lane-group q handles batch gbase+q (z replicated per row)
    float z = (q == 1) ? zb1 : zb0;
    z = (q == 2) ? zb2 : z;
    z = (q == 3) ? zb3 : z;
    float e = (col < 7) ? __builtin_amdgcn_exp2f(z * L2E) : 0.0f;
    float s = e;
    s += ROR(s, 1); s += ROR(s, 2); s += ROR(s, 4); s += ROR(s, 8);
    if (col < 7) out[(gbase + q) * 7 + col] = e * __builtin_amdgcn_rcpf(s);
}

extern "C" void kernel_launch(void* const* d_in, const int* in_sizes, int n_in,
                              void* d_out, int out_size, void* d_ws, size_t ws_size,
                              hipStream_t stream) {
    (void)in_sizes; (void)n_in; (void)out_size; (void)ws_size;
    const float* smp = (const float*)d_in[0];
    float* ws = (float*)d_ws;
    hop_prep<<<1, 256, 0, stream>>>(
        (const float*)d_in[1],  (const float*)d_in[2],   // ln_q_g, ln_q_b
        (const float*)d_in[3],                           // ln_k_g
        (const float*)d_in[5],  (const float*)d_in[6],   // ln_v_g, ln_v_b
        (const float*)d_in[7],  (const float*)d_in[8],   // Wq, bq
        (const float*)d_in[9],                           // Wk
        (const float*)d_in[11], (const float*)d_in[12],  // Wv, bv
        (const float*)d_in[13], (const float*)d_in[14],  // Wo, bo
        (const float*)d_in[15], (const float*)d_in[16],  // Wm, bm
        (const float*)d_in[17], (const float*)d_in[18],  // Wb, bb
        ws);
    hop_main<<<NBATCH * 16 / 256, 256, 0, stream>>>(smp, ws, (float*)d_out);
}